// Round 5
// baseline (98.253 us; speedup 1.0000x reference)
//
#include <hip/hip_runtime.h>
#include <math.h>

// Shapes: S=4 B=8 N=2048 K=16 D=32 H=128; rows SBN=65536, rows/sb=2048.
// R5 = R4 geometry (128-row tiles, 512 thr, grid 512 = 2 blocks/CU) with a
// slimmer phase-2 hot loop:
//  - pairwise rcp fusion: w0/A + w1/B = (w0*B + w1*A) * rcp(A*B)
//    halves v_rcp_f32 count (quarter-rate trans was 55% of hot-loop cycles)
//  - sEk/sW2 in f32 (R3-validated): removes 24 of 40 f16 converts per h8
// LDS: sX 18432 + sU max(17920,34816) + sEk 8448 + sW2 512 = 62208 B x2/CU.
typedef _Float16 half_t;
typedef __attribute__((ext_vector_type(8))) _Float16 half8;

#define EXP2F(x) __builtin_amdgcn_exp2f(x)
#define RCPF(x)  __builtin_amdgcn_rcpf(x)
#define C_SCALE 2.8853900817779268f   // 2*log2(e): tanh(z)=1-2/(1+2^(c*z))

__global__ __launch_bounds__(512, 4) void fused_kernel(
    const float* __restrict__ x, const float* __restrict__ mu,
    const float* __restrict__ tau, const float* __restrict__ W1,
    const float* __restrict__ b1, const float* __restrict__ W2,
    float* __restrict__ out) {
  __shared__ __align__(16) float sX[128][36];           // 18432 B, c*x tile
  // sU: phase1 = sW (32 rows x 560B, 16B skew per 8 float4s);
  //     phase2 = sEx (128 x 136 halfs, 272B rows). 34816 B, aliased.
  __shared__ __align__(16) unsigned char sU[128 * 272];
  __shared__ __align__(16) float sEk[16][132];          // 8448 B (f32, 528B rows)
  __shared__ __align__(16) float sW2[128];              // 512 B  (f32)

  int t = threadIdx.x;
  int row0 = blockIdx.x * 128;
  int sb = row0 >> 11;

  // ---- stage c*x tile: 128x32 = 1024 float4, coalesced ----
  const float4* x4 = (const float4*)(x + (size_t)row0 * 32);
#pragma unroll
  for (int i = 0; i < 2; ++i) {
    int j = i * 512 + t;                 // 0..1023
    int n = j >> 3, d4 = j & 7;
    float4 v = x4[j];
    v.x *= C_SCALE; v.y *= C_SCALE; v.z *= C_SCALE; v.w *= C_SCALE;
    *(float4*)&sX[n][d4 * 4] = v;
  }
  // ---- stage sW = Wx, bank-deconflicted: float4 f of row d at
  //      byte d*560 + f*16 + (f>>3)*16 (16B skew per 8 float4s -> 2-way max)
#pragma unroll
  for (int i = 0; i < 2; ++i) {
    int j = i * 512 + t;                 // 0..1023
    int d = j >> 5, f = j & 31;
    *(float4*)(sU + d * 560 + f * 16 + (f >> 3) * 16) = ((const float4*)W1)[j];
  }
  // ---- stage w2 = -2*W2 (f32) ----
  if (t < 128) sW2[t] = -2.0f * W2[t];

  // ---- ek -> sEk (f32). 1 k x 4 h per thread (512 thr = 16k x 32 hquads).
  //      Per-h chain: d ascending, mu-then-tau per d (bit-identical to R3/R4).
  {
    int k = t >> 5, h0 = (t & 31) * 4;
    const float4* mu4  = (const float4*)(mu  + ((size_t)sb * 16 + k) * 32);
    const float4* tau4 = (const float4*)(tau + ((size_t)sb * 16 + k) * 32);
    float acc[4];
    {
      float4 ba = *(const float4*)(b1 + h0);
      acc[0] = ba.x; acc[1] = ba.y; acc[2] = ba.z; acc[3] = ba.w;
    }
    const float* Wm = W1 + 32 * 128 + h0;
    const float* Wt = W1 + 64 * 128 + h0;
#pragma unroll 2
    for (int d4 = 0; d4 < 8; ++d4) {
      float4 m4 = mu4[d4], t4 = tau4[d4];
      float mv4[4] = {m4.x, m4.y, m4.z, m4.w};
      float tv4[4] = {t4.x, t4.y, t4.z, t4.w};
#pragma unroll
      for (int dd = 0; dd < 4; ++dd) {
        int d = d4 * 4 + dd;
        float4 wm = *(const float4*)(Wm + d * 128);
        float4 wt = *(const float4*)(Wt + d * 128);
        float wmv[4] = {wm.x, wm.y, wm.z, wm.w};
        float wtv[4] = {wt.x, wt.y, wt.z, wt.w};
        float mv = mv4[dd], tv = tv4[dd];
#pragma unroll
        for (int l = 0; l < 4; ++l) {
          acc[l] = fmaf(mv, wmv[l], acc[l]);
          acc[l] = fmaf(tv, wtv[l], acc[l]);
        }
      }
    }
    float4 ev;
    ev.x = EXP2F(C_SCALE * acc[0]); ev.y = EXP2F(C_SCALE * acc[1]);
    ev.z = EXP2F(C_SCALE * acc[2]); ev.w = EXP2F(C_SCALE * acc[3]);
    *(float4*)&sEk[k][h0] = ev;
  }
  __syncthreads();   // sX, sW, sW2, sEk staged

  // ---- phase 1: hx GEMM from LDS -> exp2 -> f16 regs. 4 rows x 8 h/thread.
  int hg = t & 15, rg = t >> 4;          // hg 0..15, rg 0..31
  int h0 = hg * 8, r0 = rg * 4;
  half8 hv[4];
  {
    const unsigned char* wbase = sU + hg * 32 + (hg >> 2) * 16;
    float acc[4][8];
#pragma unroll
    for (int j = 0; j < 4; ++j)
#pragma unroll
      for (int l = 0; l < 8; ++l) acc[j][l] = 0.f;
#pragma unroll 4
    for (int d = 0; d < 32; ++d) {
      float4 wa = *(const float4*)(wbase + d * 560);
      float4 wb = *(const float4*)(wbase + d * 560 + 16);
      float w[8] = {wa.x, wa.y, wa.z, wa.w, wb.x, wb.y, wb.z, wb.w};
#pragma unroll
      for (int j = 0; j < 4; ++j) {
        float xv = sX[r0 + j][d];        // broadcast among 16 lanes
#pragma unroll
        for (int l = 0; l < 8; ++l) acc[j][l] = fmaf(xv, w[l], acc[j][l]);
      }
    }
#pragma unroll
    for (int j = 0; j < 4; ++j)
#pragma unroll
      for (int l = 0; l < 8; ++l) hv[j][l] = (half_t)EXP2F(acc[j][l]);
  }
  __syncthreads();   // all sW reads done; safe to overwrite sU with sEx

  half_t (*sEx)[136] = (half_t(*)[136])sU;
#pragma unroll
  for (int j = 0; j < 4; ++j) *(half8*)&sEx[r0 + j][h0] = hv[j];
  __syncthreads();   // sEx visible

  // ---- phase 2: hot loop, 2 rows x 2 k per thread, pairwise-fused rcp ----
  int kg = t & 7, rg2 = t >> 3;          // rg2 0..63
  int rp = rg2 * 2, k0 = kg * 2;
  const half_t* exr0 = &sEx[rp][0];
  const half_t* exr1 = &sEx[rp + 1][0];
  const float* ekr0 = &sEk[k0][0];
  const float* ekr1 = &sEk[k0 + 1][0];
  float a00 = 0.f, a01 = 0.f, a10 = 0.f, a11 = 0.f;
#pragma unroll
  for (int h8 = 0; h8 < 16; ++h8) {
    half8 ex0h = *(const half8*)(exr0 + h8 * 8);
    half8 ex1h = *(const half8*)(exr1 + h8 * 8);
    float4 f0a = *(const float4*)(ekr0 + h8 * 8);
    float4 f0b = *(const float4*)(ekr0 + h8 * 8 + 4);
    float4 f1a = *(const float4*)(ekr1 + h8 * 8);
    float4 f1b = *(const float4*)(ekr1 + h8 * 8 + 4);
    float4 wa  = *(const float4*)(&sW2[h8 * 8]);
    float4 wb  = *(const float4*)(&sW2[h8 * 8 + 4]);
    float e0[8], e1[8];
#pragma unroll
    for (int j = 0; j < 8; ++j) {
      e0[j] = (float)ex0h[j]; e1[j] = (float)ex1h[j];
    }
    float f0[8] = {f0a.x, f0a.y, f0a.z, f0a.w, f0b.x, f0b.y, f0b.z, f0b.w};
    float f1[8] = {f1a.x, f1a.y, f1a.z, f1a.w, f1b.x, f1b.y, f1b.z, f1b.w};
    float w[8]  = {wa.x, wa.y, wa.z, wa.w, wb.x, wb.y, wb.z, wb.w};
#pragma unroll
    for (int p = 0; p < 4; ++p) {
      int j0 = 2 * p, j1 = 2 * p + 1;
      {
        float A = fmaf(e0[j0], f0[j0], 1.f), B = fmaf(e0[j1], f0[j1], 1.f);
        a00 = fmaf(fmaf(w[j0], B, w[j1] * A), RCPF(A * B), a00);
      }
      {
        float A = fmaf(e0[j0], f1[j0], 1.f), B = fmaf(e0[j1], f1[j1], 1.f);
        a01 = fmaf(fmaf(w[j0], B, w[j1] * A), RCPF(A * B), a01);
      }
      {
        float A = fmaf(e1[j0], f0[j0], 1.f), B = fmaf(e1[j1], f0[j1], 1.f);
        a10 = fmaf(fmaf(w[j0], B, w[j1] * A), RCPF(A * B), a10);
      }
      {
        float A = fmaf(e1[j0], f1[j0], 1.f), B = fmaf(e1[j1], f1[j1], 1.f);
        a11 = fmaf(fmaf(w[j0], B, w[j1] * A), RCPF(A * B), a11);
      }
    }
  }

  // ---- softmax over k: 2 k in-thread x 8 kg-lanes (shuffle width 8) ----
  const float l2e = 1.4426950408889634f;
  {
    float m = fmaxf(a00, a01);
#pragma unroll
    for (int s = 1; s < 8; s <<= 1) m = fmaxf(m, __shfl_xor(m, s, 8));
    float p0 = EXP2F((a00 - m) * l2e), p1 = EXP2F((a01 - m) * l2e);
    float sum = p0 + p1;
#pragma unroll
    for (int s = 1; s < 8; s <<= 1) sum += __shfl_xor(sum, s, 8);
    float inv = RCPF(sum);
    float2 o = make_float2(p0 * inv, p1 * inv);
    *(float2*)&out[(size_t)(row0 + rp) * 16 + k0] = o;
  }
  {
    float m = fmaxf(a10, a11);
#pragma unroll
    for (int s = 1; s < 8; s <<= 1) m = fmaxf(m, __shfl_xor(m, s, 8));
    float p0 = EXP2F((a10 - m) * l2e), p1 = EXP2F((a11 - m) * l2e);
    float sum = p0 + p1;
#pragma unroll
    for (int s = 1; s < 8; s <<= 1) sum += __shfl_xor(sum, s, 8);
    float inv = RCPF(sum);
    float2 o = make_float2(p0 * inv, p1 * inv);
    *(float2*)&out[(size_t)(row0 + rp + 1) * 16 + k0] = o;
  }
}

// ---------------------------------------------------------------------------
extern "C" void kernel_launch(void* const* d_in, const int* in_sizes, int n_in,
                              void* d_out, int out_size, void* d_ws, size_t ws_size,
                              hipStream_t stream) {
  const float* x   = (const float*)d_in[0];
  const float* mu  = (const float*)d_in[1];
  const float* tau = (const float*)d_in[2];
  const float* W1  = (const float*)d_in[3];
  const float* b1  = (const float*)d_in[4];
  const float* W2  = (const float*)d_in[5];
  // b2 (d_in[6]) and sum(W2) are k-uniform -> cancelled by softmax.
  float* out = (float*)d_out;
  (void)in_sizes; (void)n_in; (void)out_size; (void)d_ws; (void)ws_size;

  fused_kernel<<<512, 512, 0, stream>>>(x, mu, tau, W1, b1, W2, out);
}

// Round 6
// 93.136 us; speedup vs baseline: 1.0549x; 1.0549x over previous
//
#include <hip/hip_runtime.h>
#include <math.h>

// Shapes: S=4 B=8 N=2048 K=16 D=32 H=128; rows SBN=65536, rows/sb=2048.
// R6: UN-fuse ek back into a prep kernel (R0 structure). Rationale: fused ek
// made all 512 blocks re-read Wm/Wt (512KB/block) = 268MB L2 traffic ~8us,
// with barrier-destaggered latency stalls. prep computes ek once (128KB ws).
// Also phase-1 sX reads b128-ified: 32 ds_read_b128 instead of 128 ds_read_b32
// (-2.4us/CU LDS-pipe). Everything else identical to R5.
// LDS: sX 18432 + sU max(17920,34816) + sEk 8448 + sW2 512 = 62208 B, 2/CU.
typedef _Float16 half_t;
typedef __attribute__((ext_vector_type(8))) _Float16 half8;
typedef __attribute__((ext_vector_type(4))) _Float16 half4;

#define EXP2F(x) __builtin_amdgcn_exp2f(x)
#define RCPF(x)  __builtin_amdgcn_rcpf(x)
#define C_SCALE 2.8853900817779268f   // 2*log2(e): tanh(z)=1-2/(1+2^(c*z))

// ---------------------------------------------------------------------------
// prep: ek[(sb*16+k)*128+h] = f16( exp2(c*(mu@Wm + tau@Wt + b1)) )
// (R0-proven; per-wave W loads are 64-lane coalesced, mu/tau wave-uniform.)
// ---------------------------------------------------------------------------
__global__ __launch_bounds__(256) void prep_kernel(
    const float* __restrict__ mu, const float* __restrict__ tau,
    const float* __restrict__ W1, const float* __restrict__ b1,
    half_t* __restrict__ ek) {
  int g = blockIdx.x * 256 + threadIdx.x;   // 0..65535
  int h = g & 127, row = g >> 7;            // row = sb*16+k (512 rows)
  const float* mur  = mu  + row * 32;
  const float* taur = tau + row * 32;
  float acc = b1[h];
#pragma unroll
  for (int d = 0; d < 32; ++d) {
    acc = fmaf(mur[d],  W1[(32 + d) * 128 + h], acc);   // Wm
    acc = fmaf(taur[d], W1[(64 + d) * 128 + h], acc);   // Wt
  }
  ek[g] = (half_t)EXP2F(C_SCALE * acc);
}

// ---------------------------------------------------------------------------
__global__ __launch_bounds__(512, 4) void main_kernel(
    const float* __restrict__ x, const float* __restrict__ W1,
    const float* __restrict__ W2, const half_t* __restrict__ ek,
    float* __restrict__ out) {
  __shared__ __align__(16) float sX[128][36];           // 18432 B, c*x tile
  // sU: phase1 = sW (32 rows x 560B, 16B skew per 8 float4s);
  //     phase2 = sEx (128 x 136 halfs, 272B rows). 34816 B, aliased.
  __shared__ __align__(16) unsigned char sU[128 * 272];
  __shared__ __align__(16) float sEk[16][132];          // 8448 B (f32)
  __shared__ __align__(16) float sW2[128];              // 512 B  (f32)

  int t = threadIdx.x;
  int row0 = blockIdx.x * 128;
  int sb = row0 >> 11;

  // ---- stage sEk (f32) from f16 ek workspace: 1 half4 + cvt per thread ----
  {
    int k = t >> 5, h0 = (t & 31) * 4;
    half4 ev = *(const half4*)(ek + (size_t)sb * 2048 + k * 128 + h0);
    float4 f;
    f.x = (float)ev[0]; f.y = (float)ev[1];
    f.z = (float)ev[2]; f.w = (float)ev[3];
    *(float4*)&sEk[k][h0] = f;
  }
  // ---- stage w2 = -2*W2 (f32) ----
  if (t < 128) sW2[t] = -2.0f * W2[t];

  // ---- stage c*x tile: 128x32 = 1024 float4, coalesced ----
  const float4* x4 = (const float4*)(x + (size_t)row0 * 32);
#pragma unroll
  for (int i = 0; i < 2; ++i) {
    int j = i * 512 + t;                 // 0..1023
    int n = j >> 3, d4 = j & 7;
    float4 v = x4[j];
    v.x *= C_SCALE; v.y *= C_SCALE; v.z *= C_SCALE; v.w *= C_SCALE;
    *(float4*)&sX[n][d4 * 4] = v;
  }
  // ---- stage sW = Wx, bank-deconflicted: float4 f of row d at
  //      byte d*560 + f*16 + (f>>3)*16 (16B skew per 8 float4s -> 2-way max)
#pragma unroll
  for (int i = 0; i < 2; ++i) {
    int j = i * 512 + t;                 // 0..1023
    int d = j >> 5, f = j & 31;
    *(float4*)(sU + d * 560 + f * 16 + (f >> 3) * 16) = ((const float4*)W1)[j];
  }
  __syncthreads();   // sX, sW, sW2, sEk staged

  // ---- phase 1: hx GEMM from LDS -> exp2 -> f16 regs. 4 rows x 8 h/thread.
  //      sX read as float4 (32 b128/thread, was 128 b32). Same fma order.
  int hg = t & 15, rg = t >> 4;          // hg 0..15, rg 0..31
  int h0 = hg * 8, r0 = rg * 4;
  half8 hv[4];
  {
    const unsigned char* wbase = sU + hg * 32 + (hg >> 2) * 16;
    float acc[4][8];
#pragma unroll
    for (int j = 0; j < 4; ++j)
#pragma unroll
      for (int l = 0; l < 8; ++l) acc[j][l] = 0.f;
#pragma unroll
    for (int d4 = 0; d4 < 8; ++d4) {
      float xc[4][4];                    // [j][dd], all indices static
#pragma unroll
      for (int j = 0; j < 4; ++j) {
        float4 xv = *(const float4*)&sX[r0 + j][d4 * 4];
        xc[j][0] = xv.x; xc[j][1] = xv.y; xc[j][2] = xv.z; xc[j][3] = xv.w;
      }
#pragma unroll
      for (int dd = 0; dd < 4; ++dd) {
        int d = d4 * 4 + dd;
        float4 wa = *(const float4*)(wbase + d * 560);
        float4 wb = *(const float4*)(wbase + d * 560 + 16);
        float w[8] = {wa.x, wa.y, wa.z, wa.w, wb.x, wb.y, wb.z, wb.w};
#pragma unroll
        for (int j = 0; j < 4; ++j) {
          float xv = xc[j][dd];
#pragma unroll
          for (int l = 0; l < 8; ++l) acc[j][l] = fmaf(xv, w[l], acc[j][l]);
        }
      }
    }
#pragma unroll
    for (int j = 0; j < 4; ++j)
#pragma unroll
      for (int l = 0; l < 8; ++l) hv[j][l] = (half_t)EXP2F(acc[j][l]);
  }
  __syncthreads();   // all sW reads done; safe to overwrite sU with sEx

  half_t (*sEx)[136] = (half_t(*)[136])sU;
#pragma unroll
  for (int j = 0; j < 4; ++j) *(half8*)&sEx[r0 + j][h0] = hv[j];
  __syncthreads();   // sEx visible

  // ---- phase 2: hot loop, 2 rows x 2 k per thread, pairwise-fused rcp ----
  int kg = t & 7, rg2 = t >> 3;          // rg2 0..63
  int rp = rg2 * 2, k0 = kg * 2;
  const half_t* exr0 = &sEx[rp][0];
  const half_t* exr1 = &sEx[rp + 1][0];
  const float* ekr0 = &sEk[k0][0];
  const float* ekr1 = &sEk[k0 + 1][0];
  float a00 = 0.f, a01 = 0.f, a10 = 0.f, a11 = 0.f;
#pragma unroll
  for (int h8 = 0; h8 < 16; ++h8) {
    half8 ex0h = *(const half8*)(exr0 + h8 * 8);
    half8 ex1h = *(const half8*)(exr1 + h8 * 8);
    float4 f0a = *(const float4*)(ekr0 + h8 * 8);
    float4 f0b = *(const float4*)(ekr0 + h8 * 8 + 4);
    float4 f1a = *(const float4*)(ekr1 + h8 * 8);
    float4 f1b = *(const float4*)(ekr1 + h8 * 8 + 4);
    float4 wa  = *(const float4*)(&sW2[h8 * 8]);
    float4 wb  = *(const float4*)(&sW2[h8 * 8 + 4]);
    float e0[8], e1[8];
#pragma unroll
    for (int j = 0; j < 8; ++j) {
      e0[j] = (float)ex0h[j]; e1[j] = (float)ex1h[j];
    }
    float f0[8] = {f0a.x, f0a.y, f0a.z, f0a.w, f0b.x, f0b.y, f0b.z, f0b.w};
    float f1[8] = {f1a.x, f1a.y, f1a.z, f1a.w, f1b.x, f1b.y, f1b.z, f1b.w};
    float w[8]  = {wa.x, wa.y, wa.z, wa.w, wb.x, wb.y, wb.z, wb.w};
#pragma unroll
    for (int p = 0; p < 4; ++p) {
      int j0 = 2 * p, j1 = 2 * p + 1;
      {
        float A = fmaf(e0[j0], f0[j0], 1.f), B = fmaf(e0[j1], f0[j1], 1.f);
        a00 = fmaf(fmaf(w[j0], B, w[j1] * A), RCPF(A * B), a00);
      }
      {
        float A = fmaf(e0[j0], f1[j0], 1.f), B = fmaf(e0[j1], f1[j1], 1.f);
        a01 = fmaf(fmaf(w[j0], B, w[j1] * A), RCPF(A * B), a01);
      }
      {
        float A = fmaf(e1[j0], f0[j0], 1.f), B = fmaf(e1[j1], f0[j1], 1.f);
        a10 = fmaf(fmaf(w[j0], B, w[j1] * A), RCPF(A * B), a10);
      }
      {
        float A = fmaf(e1[j0], f1[j0], 1.f), B = fmaf(e1[j1], f1[j1], 1.f);
        a11 = fmaf(fmaf(w[j0], B, w[j1] * A), RCPF(A * B), a11);
      }
    }
  }

  // ---- softmax over k: 2 k in-thread x 8 kg-lanes (shuffle width 8) ----
  const float l2e = 1.4426950408889634f;
  {
    float m = fmaxf(a00, a01);
#pragma unroll
    for (int s = 1; s < 8; s <<= 1) m = fmaxf(m, __shfl_xor(m, s, 8));
    float p0 = EXP2F((a00 - m) * l2e), p1 = EXP2F((a01 - m) * l2e);
    float sum = p0 + p1;
#pragma unroll
    for (int s = 1; s < 8; s <<= 1) sum += __shfl_xor(sum, s, 8);
    float inv = RCPF(sum);
    float2 o = make_float2(p0 * inv, p1 * inv);
    *(float2*)&out[(size_t)(row0 + rp) * 16 + k0] = o;
  }
  {
    float m = fmaxf(a10, a11);
#pragma unroll
    for (int s = 1; s < 8; s <<= 1) m = fmaxf(m, __shfl_xor(m, s, 8));
    float p0 = EXP2F((a10 - m) * l2e), p1 = EXP2F((a11 - m) * l2e);
    float sum = p0 + p1;
#pragma unroll
    for (int s = 1; s < 8; s <<= 1) sum += __shfl_xor(sum, s, 8);
    float inv = RCPF(sum);
    float2 o = make_float2(p0 * inv, p1 * inv);
    *(float2*)&out[(size_t)(row0 + rp + 1) * 16 + k0] = o;
  }
}

// ---------------------------------------------------------------------------
extern "C" void kernel_launch(void* const* d_in, const int* in_sizes, int n_in,
                              void* d_out, int out_size, void* d_ws, size_t ws_size,
                              hipStream_t stream) {
  const float* x   = (const float*)d_in[0];
  const float* mu  = (const float*)d_in[1];
  const float* tau = (const float*)d_in[2];
  const float* W1  = (const float*)d_in[3];
  const float* b1  = (const float*)d_in[4];
  const float* W2  = (const float*)d_in[5];
  // b2 (d_in[6]) and sum(W2) are k-uniform -> cancelled by softmax.
  float* out = (float*)d_out;

  half_t* ek = (half_t*)d_ws;            // 512*128 halfs = 128 KB (R0-proven)
  (void)in_sizes; (void)n_in; (void)out_size; (void)ws_size;

  prep_kernel<<<256, 256, 0, stream>>>(mu, tau, W1, b1, ek);
  main_kernel<<<512, 512, 0, stream>>>(x, W1, W2, ek, out);
}

// Round 7
// 91.420 us; speedup vs baseline: 1.0747x; 1.0188x over previous
//
#include <hip/hip_runtime.h>
#include <math.h>

// Shapes: S=4 B=8 N=2048 K=16 D=32 H=128; rows SBN=65536, rows/sb=2048.
// R7: single kernel again — launch boundaries measured ~6.6us each (R3 calib:
// 98.68 = fill 42.5 + main 42.9 + 2x6.6), so prep+gap costs ~9.6us. ek is
// fused back WITHOUT the R5 L2-burn: Wm/Wt staged to LDS once per block
// (32KB; 16MB total L2 traffic), ek computed by 256 threads x (2k x 4h)
// (W reads reused across 2 k -> half the LDS instructions).
// Phase 2 all-f16 LDS (R4-proven absmax): R4-vs-R5 showed LDS-instr ~12cyc
// dominates cvt ~2cyc, so 5 reads/h8 + 40 cvt beats 8 reads + 24 cvt.
// LDS: sX 18432 + sW 17920 + sWmt 32768 = 69120 (sEx f16 34816 overlays
// sX+sW only) + sEk 4352 + sW2 256 = 73728 B -> 2 blocks/CU.
typedef _Float16 half_t;
typedef __attribute__((ext_vector_type(8))) _Float16 half8;
typedef __attribute__((ext_vector_type(4))) _Float16 half4;

#define EXP2F(x) __builtin_amdgcn_exp2f(x)
#define RCPF(x)  __builtin_amdgcn_rcpf(x)
#define C_SCALE 2.8853900817779268f   // 2*log2(e): tanh(z)=1-2/(1+2^(c*z))

__global__ __launch_bounds__(512, 4) void fused_kernel(
    const float* __restrict__ x, const float* __restrict__ mu,
    const float* __restrict__ tau, const float* __restrict__ W1,
    const float* __restrict__ b1, const float* __restrict__ W2,
    float* __restrict__ out) {
  // Region A (69120 B): phase A = sX[128][36] f32 | sW (32x560B skewed)
  //                     | sWmt (64x512B linear, Wm rows then Wt rows).
  //                     phase B = sEx f16 [128][136] overlays sX+sW (34816B).
  __shared__ __align__(16) unsigned char sA[69120];
  __shared__ __align__(16) half_t sEk[16][136];         // 4352 B
  __shared__ __align__(16) half_t sW2[128];             // 256 B

  float (*sX)[36] = (float(*)[36])sA;
  unsigned char* sW = sA + 18432;
  float* sWmt = (float*)(sA + 36352);                   // [64][128] f32

  int t = threadIdx.x;
  int row0 = blockIdx.x * 128;
  int sb = row0 >> 11;

  // ---- stage c*x tile: 128x32 = 1024 float4, coalesced ----
  const float4* x4 = (const float4*)(x + (size_t)row0 * 32);
#pragma unroll
  for (int i = 0; i < 2; ++i) {
    int j = i * 512 + t;                 // 0..1023
    int n = j >> 3, d4 = j & 7;
    float4 v = x4[j];
    v.x *= C_SCALE; v.y *= C_SCALE; v.z *= C_SCALE; v.w *= C_SCALE;
    *(float4*)&sX[n][d4 * 4] = v;
  }
  // ---- stage sW = Wx rows 0..31, bank-deconflicted (16B skew per 8 f4) ----
#pragma unroll
  for (int i = 0; i < 2; ++i) {
    int j = i * 512 + t;                 // 0..1023
    int d = j >> 5, f = j & 31;
    *(float4*)(sW + d * 560 + f * 16 + (f >> 3) * 16) = ((const float4*)W1)[j];
  }
  // ---- stage sWmt = W1 rows 32..95 (Wm then Wt), linear: 2048 float4 ----
  {
    const float4* wmt4 = (const float4*)(W1 + 32 * 128);
    float4* dst = (float4*)sWmt;
#pragma unroll
    for (int i = 0; i < 4; ++i) dst[i * 512 + t] = wmt4[i * 512 + t];
  }
  // ---- stage w2h = f16(-2*W2) ----
  if (t < 16) {
    float4 a = ((const float4*)W2)[2 * t];
    float4 b = ((const float4*)W2)[2 * t + 1];
    half8 hv;
    hv[0] = (half_t)(-2.f * a.x); hv[1] = (half_t)(-2.f * a.y);
    hv[2] = (half_t)(-2.f * a.z); hv[3] = (half_t)(-2.f * a.w);
    hv[4] = (half_t)(-2.f * b.x); hv[5] = (half_t)(-2.f * b.y);
    hv[6] = (half_t)(-2.f * b.z); hv[7] = (half_t)(-2.f * b.w);
    *(half8*)&sW2[t * 8] = hv;
  }
  __syncthreads();   // sX, sW, sWmt, sW2 staged

  // ---- ek -> sEk (f16): 256 threads x (2 k x 4 h); W reads from LDS,
  //      reused across the 2 k. Per-h chain: d ascending, mu-then-tau per d
  //      (bit-identical to R5/R6 -> f16 value identical to R0/R4/R6 ek).
  if (t < 256) {
    int k0 = (t >> 5) * 2, h0 = (t & 31) * 4;
    const float4* mu4a  = (const float4*)(mu  + ((size_t)sb * 16 + k0) * 32);
    const float4* tau4a = (const float4*)(tau + ((size_t)sb * 16 + k0) * 32);
    const float4* mu4b  = mu4a + 8;      // row k0+1
    const float4* tau4b = tau4a + 8;
    float acc0[4], acc1[4];
    {
      float4 ba = *(const float4*)(b1 + h0);
      acc0[0] = ba.x; acc0[1] = ba.y; acc0[2] = ba.z; acc0[3] = ba.w;
      acc1[0] = ba.x; acc1[1] = ba.y; acc1[2] = ba.z; acc1[3] = ba.w;
    }
    const float* Wm = sWmt + h0;
    const float* Wt = sWmt + 32 * 128 + h0;
#pragma unroll 2
    for (int d4 = 0; d4 < 8; ++d4) {
      float4 ma = mu4a[d4], ta = tau4a[d4];
      float4 mb = mu4b[d4], tb = tau4b[d4];
      float mva[4] = {ma.x, ma.y, ma.z, ma.w};
      float tva[4] = {ta.x, ta.y, ta.z, ta.w};
      float mvb[4] = {mb.x, mb.y, mb.z, mb.w};
      float tvb[4] = {tb.x, tb.y, tb.z, tb.w};
#pragma unroll
      for (int dd = 0; dd < 4; ++dd) {
        int d = d4 * 4 + dd;
        float4 wm = *(const float4*)(Wm + d * 128);
        float4 wt = *(const float4*)(Wt + d * 128);
        float wmv[4] = {wm.x, wm.y, wm.z, wm.w};
        float wtv[4] = {wt.x, wt.y, wt.z, wt.w};
#pragma unroll
        for (int l = 0; l < 4; ++l) {
          acc0[l] = fmaf(mva[dd], wmv[l], acc0[l]);
          acc0[l] = fmaf(tva[dd], wtv[l], acc0[l]);
          acc1[l] = fmaf(mvb[dd], wmv[l], acc1[l]);
          acc1[l] = fmaf(tvb[dd], wtv[l], acc1[l]);
        }
      }
    }
    half4 h0v, h1v;
#pragma unroll
    for (int l = 0; l < 4; ++l) {
      h0v[l] = (half_t)EXP2F(C_SCALE * acc0[l]);
      h1v[l] = (half_t)EXP2F(C_SCALE * acc1[l]);
    }
    *(half4*)&sEk[k0][h0] = h0v;
    *(half4*)&sEk[k0 + 1][h0] = h1v;
  }

  // ---- phase 1: hx GEMM from LDS -> exp2 -> f16 regs. 4 rows x 8 h/thread.
  int hg = t & 15, rg = t >> 4;          // hg 0..15, rg 0..31
  int h0 = hg * 8, r0 = rg * 4;
  half8 hv[4];
  {
    const unsigned char* wbase = sW + hg * 32 + (hg >> 2) * 16;
    float acc[4][8];
#pragma unroll
    for (int j = 0; j < 4; ++j)
#pragma unroll
      for (int l = 0; l < 8; ++l) acc[j][l] = 0.f;
#pragma unroll
    for (int d4 = 0; d4 < 8; ++d4) {
      float xc[4][4];                    // [j][dd], static indices
#pragma unroll
      for (int j = 0; j < 4; ++j) {
        float4 xv = *(const float4*)&sX[r0 + j][d4 * 4];
        xc[j][0] = xv.x; xc[j][1] = xv.y; xc[j][2] = xv.z; xc[j][3] = xv.w;
      }
#pragma unroll
      for (int dd = 0; dd < 4; ++dd) {
        int d = d4 * 4 + dd;
        float4 wa = *(const float4*)(wbase + d * 560);
        float4 wb = *(const float4*)(wbase + d * 560 + 16);
        float w[8] = {wa.x, wa.y, wa.z, wa.w, wb.x, wb.y, wb.z, wb.w};
#pragma unroll
        for (int j = 0; j < 4; ++j) {
          float xv = xc[j][dd];
#pragma unroll
          for (int l = 0; l < 8; ++l) acc[j][l] = fmaf(xv, w[l], acc[j][l]);
        }
      }
    }
#pragma unroll
    for (int j = 0; j < 4; ++j)
#pragma unroll
      for (int l = 0; l < 8; ++l) hv[j][l] = (half_t)EXP2F(acc[j][l]);
  }
  __syncthreads();   // all sX/sW/sWmt reads done; safe to overlay sEx

  half_t (*sEx)[136] = (half_t(*)[136])sA;
#pragma unroll
  for (int j = 0; j < 4; ++j) *(half8*)&sEx[r0 + j][h0] = hv[j];
  __syncthreads();   // sEx visible

  // ---- phase 2: 2 rows x 2 k per thread, f16 loads (5/h8), pairwise rcp ----
  int kg = t & 7, rg2 = t >> 3;          // rg2 0..63
  int rp = rg2 * 2, k0 = kg * 2;
  const half_t* exr0 = &sEx[rp][0];
  const half_t* exr1 = &sEx[rp + 1][0];
  const half_t* ekr0 = &sEk[k0][0];
  const half_t* ekr1 = &sEk[k0 + 1][0];
  float a00 = 0.f, a01 = 0.f, a10 = 0.f, a11 = 0.f;
#pragma unroll
  for (int h8 = 0; h8 < 16; ++h8) {
    half8 ex0h = *(const half8*)(exr0 + h8 * 8);
    half8 ex1h = *(const half8*)(exr1 + h8 * 8);
    half8 ek0h = *(const half8*)(ekr0 + h8 * 8);
    half8 ek1h = *(const half8*)(ekr1 + h8 * 8);
    half8 wvh  = *(const half8*)(&sW2[h8 * 8]);
    float e0[8], e1[8], f0[8], f1[8], w[8];
#pragma unroll
    for (int j = 0; j < 8; ++j) {
      e0[j] = (float)ex0h[j]; e1[j] = (float)ex1h[j];
      f0[j] = (float)ek0h[j]; f1[j] = (float)ek1h[j];
      w[j]  = (float)wvh[j];
    }
#pragma unroll
    for (int p = 0; p < 4; ++p) {
      int j0 = 2 * p, j1 = 2 * p + 1;
      {
        float A = fmaf(e0[j0], f0[j0], 1.f), B = fmaf(e0[j1], f0[j1], 1.f);
        a00 = fmaf(fmaf(w[j0], B, w[j1] * A), RCPF(A * B), a00);
      }
      {
        float A = fmaf(e0[j0], f1[j0], 1.f), B = fmaf(e0[j1], f1[j1], 1.f);
        a01 = fmaf(fmaf(w[j0], B, w[j1] * A), RCPF(A * B), a01);
      }
      {
        float A = fmaf(e1[j0], f0[j0], 1.f), B = fmaf(e1[j1], f0[j1], 1.f);
        a10 = fmaf(fmaf(w[j0], B, w[j1] * A), RCPF(A * B), a10);
      }
      {
        float A = fmaf(e1[j0], f1[j0], 1.f), B = fmaf(e1[j1], f1[j1], 1.f);
        a11 = fmaf(fmaf(w[j0], B, w[j1] * A), RCPF(A * B), a11);
      }
    }
  }

  // ---- softmax over k: 2 k in-thread x 8 kg-lanes (shuffle width 8) ----
  const float l2e = 1.4426950408889634f;
  {
    float m = fmaxf(a00, a01);
#pragma unroll
    for (int s = 1; s < 8; s <<= 1) m = fmaxf(m, __shfl_xor(m, s, 8));
    float p0 = EXP2F((a00 - m) * l2e), p1 = EXP2F((a01 - m) * l2e);
    float sum = p0 + p1;
#pragma unroll
    for (int s = 1; s < 8; s <<= 1) sum += __shfl_xor(sum, s, 8);
    float inv = RCPF(sum);
    float2 o = make_float2(p0 * inv, p1 * inv);
    *(float2*)&out[(size_t)(row0 + rp) * 16 + k0] = o;
  }
  {
    float m = fmaxf(a10, a11);
#pragma unroll
    for (int s = 1; s < 8; s <<= 1) m = fmaxf(m, __shfl_xor(m, s, 8));
    float p0 = EXP2F((a10 - m) * l2e), p1 = EXP2F((a11 - m) * l2e);
    float sum = p0 + p1;
#pragma unroll
    for (int s = 1; s < 8; s <<= 1) sum += __shfl_xor(sum, s, 8);
    float inv = RCPF(sum);
    float2 o = make_float2(p0 * inv, p1 * inv);
    *(float2*)&out[(size_t)(row0 + rp + 1) * 16 + k0] = o;
  }
}

// ---------------------------------------------------------------------------
extern "C" void kernel_launch(void* const* d_in, const int* in_sizes, int n_in,
                              void* d_out, int out_size, void* d_ws, size_t ws_size,
                              hipStream_t stream) {
  const float* x   = (const float*)d_in[0];
  const float* mu  = (const float*)d_in[1];
  const float* tau = (const float*)d_in[2];
  const float* W1  = (const float*)d_in[3];
  const float* b1  = (const float*)d_in[4];
  const float* W2  = (const float*)d_in[5];
  // b2 (d_in[6]) and sum(W2) are k-uniform -> cancelled by softmax.
  float* out = (float*)d_out;
  (void)in_sizes; (void)n_in; (void)out_size; (void)d_ws; (void)ws_size;

  fused_kernel<<<512, 512, 0, stream>>>(x, mu, tau, W1, b1, W2, out);
}